// Round 11
// baseline (175.256 us; speedup 1.0000x reference)
//
#include <hip/hip_runtime.h>
#include <hip/hip_bf16.h>
#include <math.h>

#define N 8192
#define D 128
#define NELEM (N * D)
#define KNN 10
#define EPSF 1e-10f
#define RT 16       // rows per tile (4KB staged per tile)
#define NSLICE 16
#define RH 512      // rows per slice (NSLICE*RH == N)
#define BIGF 3.0e38f

typedef unsigned short ushort_t;
typedef short bf16x8 __attribute__((ext_vector_type(8)));
typedef float f32x4 __attribute__((ext_vector_type(4)));

// ---- branchless sorted-insert: l ascending, keep smallest L ----
template <int L>
__device__ __forceinline__ void insM(float (&l)[L], float v) {
  #pragma unroll
  for (int q = L - 1; q >= 1; --q)
    asm("v_med3_f32 %0, %1, %2, %3"
        : "=v"(l[q]) : "v"(l[q - 1]), "v"(l[q]), "v"(v));
  asm("v_min_f32 %0, %1, %2" : "=v"(l[0]) : "v"(l[0]), "v"(v));
}

// plain version for the small kernels
template <int L>
__device__ __forceinline__ void insP(float (&l)[L], float v) {
  #pragma unroll
  for (int q = L - 1; q >= 1; --q)
    l[q] = __builtin_amdgcn_fmed3f(l[q - 1], l[q], v);
  l[0] = fminf(l[0], v);
}

// ---------------- Kernel 0: fused prep: bf16(x), bf16(-2x), sq ----------------
__global__ void prep_kernel(const float* __restrict__ xc,
                            const float* __restrict__ xr,
                            ushort_t* __restrict__ xb,    // [2][N][D] bf16(x)
                            ushort_t* __restrict__ xa,    // [2][N][D] bf16(-2x)
                            float* __restrict__ sq) {     // [2][N] fp32
  int wid  = (blockIdx.x * blockDim.x + threadIdx.x) >> 6;  // row in [0, 2N)
  int lane = threadIdx.x & 63;
  if (wid >= 2 * N) return;
  const float* x = (wid < N) ? xc : xr;
  int row = (wid < N) ? wid : wid - N;
  float2 v = *reinterpret_cast<const float2*>(x + (size_t)row * D + lane * 2);
  float s = v.x * v.x + v.y * v.y;
  #pragma unroll
  for (int off = 32; off; off >>= 1) s += __shfl_xor(s, off, 64);
  if (lane == 0) sq[wid] = s;
  auto cvt = [](float f) -> unsigned int {
    unsigned int b = __float_as_uint(f);
    return (b + 0x7FFFu + ((b >> 16) & 1u)) >> 16;   // RTNE
  };
  unsigned int pb = cvt(v.x) | (cvt(v.y) << 16);
  unsigned int pa = cvt(-2.f * v.x) | (cvt(-2.f * v.y) << 16);
  *reinterpret_cast<unsigned int*>(xb + (size_t)wid * D + lane * 2) = pb;
  *reinterpret_cast<unsigned int*>(xa + (size_t)wid * D + lane * 2) = pa;
}

// ---------------- Kernel 1: MFMA distance + per-column top-10 ----------------
// BARRIER-FREE 1-WAVE BLOCKS + COUNTED VMCNT (T4): LDS is wave-private, so
// staging is sequenced purely by s_waitcnt vmcnt(4) — next tile's 4 loads stay
// in flight across the compute, never drained to 0 in the loop (m233: the
// vmcnt(0)+barrier drain was ~72% of the 2-phase loop's critical path).
// grid = 8192 x 64thr: mat = bid>>12, colgrp = (bid>>4)&255, slice = bid&15.
// Wave owns 32 cols; streams RH=512 rows in RT=16 tiles (4KB, dbuf).
// LDS fragment-ordered (R5: zero bank conflicts). acc init = sq[row];
// A = bf16(-2x) => acc = key = sq_row - 2*dot. Diagonal poisoned on overlap.
__global__ __launch_bounds__(64, 4) void knn_mfma(
    const ushort_t* __restrict__ xb,    // bf16(x)   [2][N][D]
    const ushort_t* __restrict__ xa,    // bf16(-2x) [2][N][D]
    const float* __restrict__ sq,       // [2][N]
    float* __restrict__ partial) {      // [2*N][NSLICE][KNN]
  __shared__ __align__(16) ushort_t Abuf[2][RT * D];   // 2 x 4KB (wave-private)
  __shared__ __align__(16) float SQs[RH];              // 2KB slice norms

  const int bid = blockIdx.x;
  const int mat = bid >> 12;
  const int colgrp = (bid >> 4) & 255;
  const int slice = bid & 15;
  const ushort_t* __restrict__ XB = xb + (size_t)mat * NELEM;
  const ushort_t* __restrict__ XA = xa + (size_t)mat * NELEM;
  const float* __restrict__ SQ = sq + mat * N;
  const int r0 = slice * RH;
  const int l = threadIdx.x;            // 0..63
  const int c0 = colgrp * 32;           // wave's column base (32 cols)

  // --- stage slice norms once (2 gload_lds) ---
  #pragma unroll
  for (int h = 0; h < 2; ++h) {
    const float* gs = SQ + r0 + h * 256 + l * 4;
    float* dsts = &SQs[h * 256];
    __builtin_amdgcn_global_load_lds(
        (const __attribute__((address_space(1))) void*)gs,
        (__attribute__((address_space(3))) void*)dsts, 16, 0, 0);
  }

  // --- B fragments (owned cols, full K=128) in registers: 32 VGPR ---
  bf16x8 bfr[2][4];
  #pragma unroll
  for (int j = 0; j < 2; ++j) {
    const ushort_t* p = XB + (size_t)(c0 + j * 16 + (l & 15)) * D + (l >> 4) * 8;
    #pragma unroll
    for (int kk = 0; kk < 4; ++kk)
      bfr[j][kk] = *reinterpret_cast<const bf16x8*>(p + kk * 32);
  }

  float cand[2][KNN];
  #pragma unroll
  for (int j = 0; j < 2; ++j)
    #pragma unroll
    for (int q = 0; q < KNN; ++q) cand[j][q] = BIGF;

  // --- fragment-ordered staging: region kk (1KB) holds row=(l&15),
  //     kchunk = kk*4 + (l>>4); gload_lds writes base + lane*16 linearly ---
  const ushort_t* gbase[4];
  #pragma unroll
  for (int kk = 0; kk < 4; ++kk)
    gbase[kk] = XA + (size_t)(r0 + (l & 15)) * D + (kk * 4 + (l >> 4)) * 8;

  auto stage = [&](int tt, int bb) {
    #pragma unroll
    for (int kk = 0; kk < 4; ++kk) {
      const ushort_t* g = gbase[kk] + (size_t)tt * (RT * D);
      ushort_t* dst = &Abuf[bb][kk * 512];
      __builtin_amdgcn_global_load_lds(
          (const __attribute__((address_space(1))) void*)g,
          (__attribute__((address_space(3))) void*)dst, 16, 0, 0);
    }
  };

  stage(0, 0);
  asm volatile("s_waitcnt vmcnt(0)" ::: "memory");   // prologue only

  constexpr int T = RH / RT;   // 32 tiles
  for (int tt = 0; tt < T; ++tt) {
    const int cur = tt & 1;
    if (tt < T - 1) {
      stage(tt + 1, cur ^ 1);                        // 4 loads in flight
      asm volatile("s_waitcnt vmcnt(4)" ::: "memory"); // tile tt retired
    } else {
      asm volatile("s_waitcnt vmcnt(0)" ::: "memory");
    }

    // C-init: acc = sq[row]; rows: (l>>4)*4 + r (broadcast LDS read)
    f32x4 sqi = *reinterpret_cast<const f32x4*>(&SQs[tt * RT + ((l >> 4) << 2)]);

    f32x4 acc[2];
    #pragma unroll
    for (int j = 0; j < 2; ++j) acc[j] = sqi;

    #pragma unroll
    for (int kk = 0; kk < 4; ++kk) {
      bf16x8 af = *reinterpret_cast<const bf16x8*>(&Abuf[cur][kk * 512 + l * 8]);
      #pragma unroll
      for (int j = 0; j < 2; ++j)
        acc[j] = __builtin_amdgcn_mfma_f32_16x16x32_bf16(af, bfr[j][kk],
                                                         acc[j], 0, 0, 0);
    }

    // --- self-exclusion: poison row==col on (rare) diagonal tiles ---
    const int rbase = r0 + tt * RT;
    const int idiff = c0 - rbase;          // overlap iff idiff in [-31, 15]
    if ((unsigned)(idiff + 31) < 47u) {    // wave-uniform branch
      #pragma unroll
      for (int j = 0; j < 2; ++j) {
        const int dd = idiff + j * 16 + (l & 15) - ((l >> 4) << 2);
        #pragma unroll
        for (int r = 0; r < 4; ++r)
          if (dd == r) acc[j][r] = BIGF;   // cndmask after unroll
      }
    }

    // branchless top-10 insert: 10 VALU ops/key, 2 lists interleaved for ILP
    #pragma unroll
    for (int r = 0; r < 4; ++r)
      #pragma unroll
      for (int j = 0; j < 2; ++j)
        insM<KNN>(cand[j], acc[j][r]);
  }

  // --- merge the 4 lane-groups holding the same columns (xor 16, then 32) ---
  #pragma unroll
  for (int step = 16; step <= 32; step <<= 1)
    #pragma unroll
    for (int j = 0; j < 2; ++j)
      #pragma unroll
      for (int q = 0; q < KNN; ++q) {
        float o = __shfl_xor(cand[j][q], step, 64);
        insM<KNN>(cand[j], o);
      }

  // --- write slice-partial top-10 ---
  if (l < 16) {
    #pragma unroll
    for (int j = 0; j < 2; ++j) {
      const int c = c0 + j * 16 + l;
      float* dst = partial + ((size_t)(mat * N + c) * NSLICE + slice) * KNN;
      #pragma unroll
      for (int q = 0; q < KNN; ++q) dst[q] = cand[j][q];
    }
  }
}

// ------- Kernel 2: fused slice-merge + sqrt + Sinkhorn (Toeplitz scans) -----
__global__ void sink_kernel(const float* __restrict__ partial,
                            const float* __restrict__ sq,
                            float* __restrict__ ps) {
  int s = blockIdx.x * blockDim.x + threadIdx.x;
  if (s >= N) return;
  constexpr float E1 = 0.36787944117144233f;  // exp(-1)

  float a[KNN], b[KNN];
  #pragma unroll
  for (int m = 0; m < 2; ++m) {
    float best[KNN];
    #pragma unroll
    for (int q = 0; q < KNN; ++q) best[q] = BIGF;
    const float* p = partial + (size_t)(m * N + s) * NSLICE * KNN;
    for (int c = 0; c < NSLICE * KNN; ++c) insP<KNN>(best, p[c]);
    const float sqc = sq[m * N + s];
    float* dst = m ? b : a;
    #pragma unroll
    for (int q = 0; q < KNN; ++q)
      dst[q] = sqrtf(fmaxf(best[q] + sqc, 1e-12f));
  }

  float suma = 0.f, sumb = 0.f;
  #pragma unroll
  for (int q = 0; q < KNN; ++q) { suma += a[q]; sumb += b[q]; }
  float rsa = __builtin_amdgcn_rcpf(suma + EPSF);
  float rsb = __builtin_amdgcn_rcpf(sumb + EPSF);
  #pragma unroll
  for (int q = 0; q < KNN; ++q) { a[q] *= rsa; b[q] *= rsb; }

  float u_[KNN], v_[KNN];
  #pragma unroll
  for (int q = 0; q < KNN; ++q) u_[q] = 1.f;

  #pragma unroll 1
  for (int it = 0; it < 50; ++it) {
    float L[KNN], S[KNN];
    L[0] = u_[0];
    #pragma unroll
    for (int q = 1; q < KNN; ++q) L[q] = fmaf(E1, L[q - 1], u_[q]);
    S[KNN - 1] = u_[KNN - 1];
    #pragma unroll
    for (int q = KNN - 2; q >= 0; --q) S[q] = fmaf(E1, S[q + 1], u_[q]);
    #pragma unroll
    for (int q = 0; q < KNN; ++q) {
      float den = (q < KNN - 1) ? fmaf(E1, S[q + 1], L[q]) : L[KNN - 1];
      v_[q] = b[q] * __builtin_amdgcn_rcpf(den + EPSF);
    }
    L[0] = v_[0];
    #pragma unroll
    for (int q = 1; q < KNN; ++q) L[q] = fmaf(E1, L[q - 1], v_[q]);
    S[KNN - 1] = v_[KNN - 1];
    #pragma unroll
    for (int q = KNN - 2; q >= 0; --q) S[q] = fmaf(E1, S[q + 1], v_[q]);
    #pragma unroll
    for (int q = 0; q < KNN; ++q) {
      float den = (q < KNN - 1) ? fmaf(E1, S[q + 1], L[q]) : L[KNN - 1];
      u_[q] = a[q] * __builtin_amdgcn_rcpf(den + EPSF);
    }
  }
  {
    float L[KNN], S[KNN];
    L[0] = u_[0];
    #pragma unroll
    for (int q = 1; q < KNN; ++q) L[q] = fmaf(E1, L[q - 1], u_[q]);
    S[KNN - 1] = u_[KNN - 1];
    #pragma unroll
    for (int q = KNN - 2; q >= 0; --q) S[q] = fmaf(E1, S[q + 1], u_[q]);
    #pragma unroll
    for (int q = 0; q < KNN; ++q) {
      float den = (q < KNN - 1) ? fmaf(E1, S[q + 1], L[q]) : L[KNN - 1];
      v_[q] = b[q] * __builtin_amdgcn_rcpf(den + EPSF);
    }
  }
  float cost = 0.f;
  #pragma unroll
  for (int i = 0; i < KNN; ++i) {
    float accr = 0.f;
    #pragma unroll
    for (int j = 0; j < KNN; ++j) {
      const int dd = i > j ? i - j : j - i;
      const float wgt = 0.1f * (float)dd * __builtin_expf(-(float)dd); // folds
      accr = fmaf(wgt, v_[j], accr);
    }
    cost = fmaf(u_[i], accr, cost);
  }
  ps[s] = cost;
}

// ---------------- Kernel 3: mean reduce ----------------
__global__ void reduce_kernel(const float* __restrict__ ps, float* __restrict__ out) {
  __shared__ float red[256];
  int tid = threadIdx.x;
  float s = 0.f;
  for (int i = tid; i < N; i += 256) s += ps[i];
  red[tid] = s;
  __syncthreads();
  #pragma unroll
  for (int off = 128; off > 0; off >>= 1) {
    if (tid < off) red[tid] += red[tid + off];
    __syncthreads();
  }
  if (tid == 0) out[0] = red[0] * (1.0f / N);
}

extern "C" void kernel_launch(void* const* d_in, const int* in_sizes, int n_in,
                              void* d_out, int out_size, void* d_ws, size_t ws_size,
                              hipStream_t stream) {
  const float* xc = (const float*)d_in[0];
  const float* xr = (const float*)d_in[1];
  float* out = (float*)d_out;
  char* wsb = (char*)d_ws;

  float* sq       = (float*)wsb;                                // 2N f32 (64KB)
  ushort_t* xb    = (ushort_t*)(wsb + (1u << 16));              // 4MB
  ushort_t* xa    = (ushort_t*)(wsb + (1u << 16) + (4u << 20)); // 4MB
  float* partial  = (float*)(wsb + (1u << 16) + (8u << 20));    // 2N*160 f32
  float* ps       = partial + (size_t)2 * N * NSLICE * KNN;     // N f32

  prep_kernel<<<dim3(2 * N / 4), dim3(256), 0, stream>>>(xc, xr, xb, xa, sq);
  knn_mfma<<<dim3(8192), dim3(64), 0, stream>>>(xb, xa, sq, partial);
  sink_kernel<<<dim3(N / 64), dim3(64), 0, stream>>>(partial, sq, ps);
  reduce_kernel<<<dim3(1), dim3(256), 0, stream>>>(ps, out);
}

// Round 12
// 114.778 us; speedup vs baseline: 1.5269x; 1.5269x over previous
//
#include <hip/hip_runtime.h>
#include <hip/hip_bf16.h>
#include <math.h>

#define N 8192
#define D 128
#define NELEM (N * D)
#define KNN 10
#define EPSF 1e-10f
#define RT 32       // rows per tile
#define NSLICE 8
#define RH 1024     // rows per slice (NSLICE*RH == N)
#define BIGF 3.0e38f

typedef unsigned short ushort_t;
typedef short bf16x8 __attribute__((ext_vector_type(8)));
typedef float f32x4 __attribute__((ext_vector_type(4)));

// ---- branchless sorted-insert: l ascending, keep smallest L ----
template <int L>
__device__ __forceinline__ void insM(float (&l)[L], float v) {
  #pragma unroll
  for (int q = L - 1; q >= 1; --q)
    asm("v_med3_f32 %0, %1, %2, %3"
        : "=v"(l[q]) : "v"(l[q - 1]), "v"(l[q]), "v"(v));
  asm("v_min_f32 %0, %1, %2" : "=v"(l[0]) : "v"(l[0]), "v"(v));
}

// plain version for the small kernels
template <int L>
__device__ __forceinline__ void insP(float (&l)[L], float v) {
  #pragma unroll
  for (int q = L - 1; q >= 1; --q)
    l[q] = __builtin_amdgcn_fmed3f(l[q - 1], l[q], v);
  l[0] = fminf(l[0], v);
}

// ---------------- Kernel 0: fused prep: bf16(x), bf16(-2x), sq ----------------
__global__ void prep_kernel(const float* __restrict__ xc,
                            const float* __restrict__ xr,
                            ushort_t* __restrict__ xb,    // [2][N][D] bf16(x)
                            ushort_t* __restrict__ xa,    // [2][N][D] bf16(-2x)
                            float* __restrict__ sq) {     // [2][N] fp32
  int wid  = (blockIdx.x * blockDim.x + threadIdx.x) >> 6;  // row in [0, 2N)
  int lane = threadIdx.x & 63;
  if (wid >= 2 * N) return;
  const float* x = (wid < N) ? xc : xr;
  int row = (wid < N) ? wid : wid - N;
  float2 v = *reinterpret_cast<const float2*>(x + (size_t)row * D + lane * 2);
  float s = v.x * v.x + v.y * v.y;
  #pragma unroll
  for (int off = 32; off; off >>= 1) s += __shfl_xor(s, off, 64);
  if (lane == 0) sq[wid] = s;
  auto cvt = [](float f) -> unsigned int {
    unsigned int b = __float_as_uint(f);
    return (b + 0x7FFFu + ((b >> 16) & 1u)) >> 16;   // RTNE
  };
  unsigned int pb = cvt(v.x) | (cvt(v.y) << 16);
  unsigned int pa = cvt(-2.f * v.x) | (cvt(-2.f * v.y) << 16);
  *reinterpret_cast<unsigned int*>(xb + (size_t)wid * D + lane * 2) = pb;
  *reinterpret_cast<unsigned int*>(xa + (size_t)wid * D + lane * 2) = pa;
}

// ---------------- Kernel 1: MFMA distance + per-column top-10 ----------------
// grid = 1024: mat = bid>>9, colblk = (bid>>3)&63, slice = bid&7.
// Block: 4 waves x 32 cols = 128 cols, iterates RH=1024 rows in RT=32 tiles.
// COUNTED-VMCNT schedule (T4, m218): per tile
//   stage(t+1) -> vmcnt(2) [t's loads retired, t+1's IN FLIGHT] ->
//   raw s_barrier (no drain!) -> compute(t) -> raw s_barrier (WAR).
// R9's trailing vmcnt(0)+__syncthreads drained the just-issued prefetch every
// tile (m233's "2-phase stall"); this keeps 2 loads in flight across barriers.
// LDS fragment-ordered (R5: zero bank conflicts). acc init = sq[row];
// A = bf16(-2x) => acc = key = sq_row - 2*dot. Diagonal poisoned on overlap.
__global__ __launch_bounds__(256) void knn_mfma(
    const ushort_t* __restrict__ xb,    // bf16(x)   [2][N][D]
    const ushort_t* __restrict__ xa,    // bf16(-2x) [2][N][D]
    const float* __restrict__ sq,       // [2][N]
    float* __restrict__ partial) {      // [2*N][NSLICE][KNN]
  __shared__ __align__(16) ushort_t Abuf[2][RT * D];   // 2 x 8KB
  __shared__ __align__(16) float SQs[RH];              // 4KB slice norms

  const int bid = blockIdx.x;
  const int mat = bid >> 9;
  const int colblk = (bid >> 3) & 63;
  const int slice = bid & 7;
  const ushort_t* __restrict__ XB = xb + (size_t)mat * NELEM;
  const ushort_t* __restrict__ XA = xa + (size_t)mat * NELEM;
  const float* __restrict__ SQ = sq + mat * N;
  const int r0 = slice * RH;
  const int t = threadIdx.x;
  const int w = t >> 6, l = t & 63;
  const int c0w = colblk * 128 + w * 32;     // wave's column base (32 cols)

  // --- stage slice norms once: wave w covers SQs[w*256 .. +255] ---
  {
    const float* gs = SQ + r0 + w * 256 + l * 4;
    float* dsts = &SQs[w * 256];
    __builtin_amdgcn_global_load_lds(
        (const __attribute__((address_space(1))) void*)gs,
        (__attribute__((address_space(3))) void*)dsts, 16, 0, 0);
  }

  // --- B fragments (owned cols, full K=128) in registers: 32 VGPR ---
  bf16x8 bfr[2][4];
  #pragma unroll
  for (int j = 0; j < 2; ++j) {
    const ushort_t* p = XB + (size_t)(c0w + j * 16 + (l & 15)) * D + (l >> 4) * 8;
    #pragma unroll
    for (int kk = 0; kk < 4; ++kk)
      bfr[j][kk] = *reinterpret_cast<const bf16x8*>(p + kk * 32);
  }

  float cand[2][KNN];
  #pragma unroll
  for (int j = 0; j < 2; ++j)
    #pragma unroll
    for (int q = 0; q < KNN; ++q) cand[j][q] = BIGF;

  // --- per-lane global source pointers for fragment-ordered staging ---
  // region rg = 2*w+h (1KB each); holds row=ii*16+(l&15), kchunk=kk*4+(l>>4)
  const ushort_t* gbase[2];
  #pragma unroll
  for (int h = 0; h < 2; ++h) {
    const int rg = 2 * w + h;
    const int kk = rg >> 1, ii = rg & 1;
    const int row = ii * 16 + (l & 15);
    const int ch  = kk * 4 + (l >> 4);
    gbase[h] = XA + (size_t)(r0 + row) * D + ch * 8;
  }

  auto stage = [&](int tt, int bb) {
    #pragma unroll
    for (int h = 0; h < 2; ++h) {
      const ushort_t* g = gbase[h] + (size_t)tt * (RT * D);
      ushort_t* dst = &Abuf[bb][(2 * w + h) * 512];
      __builtin_amdgcn_global_load_lds(
          (const __attribute__((address_space(1))) void*)g,
          (__attribute__((address_space(3))) void*)dst, 16, 0, 0);
    }
  };

  stage(0, 0);
  asm volatile("s_waitcnt vmcnt(0)" ::: "memory");   // prologue only
  __builtin_amdgcn_s_barrier();
  asm volatile("" ::: "memory");

  constexpr int T = RH / RT;   // 32 tiles
  for (int tt = 0; tt < T; ++tt) {
    const int cur = tt & 1;
    if (tt < T - 1) {
      stage(tt + 1, cur ^ 1);                          // 2 loads -> in flight
      asm volatile("s_waitcnt vmcnt(2)" ::: "memory"); // tile tt retired only
    } else {
      asm volatile("s_waitcnt vmcnt(0)" ::: "memory");
    }
    __builtin_amdgcn_s_barrier();    // all waves' tile-tt LDS writes visible
    asm volatile("" ::: "memory");

    // C-init: acc = sq[row]; rows: i*16 + (l>>4)*4 + r (broadcast reads)
    f32x4 sqi[2];
    #pragma unroll
    for (int i = 0; i < 2; ++i)
      sqi[i] = *reinterpret_cast<const f32x4*>(
          &SQs[tt * RT + i * 16 + ((l >> 4) << 2)]);

    f32x4 acc[2][2];
    #pragma unroll
    for (int i = 0; i < 2; ++i)
      #pragma unroll
      for (int j = 0; j < 2; ++j) acc[i][j] = sqi[i];

    #pragma unroll
    for (int kk = 0; kk < 4; ++kk) {
      bf16x8 af[2];
      #pragma unroll
      for (int i = 0; i < 2; ++i)
        af[i] = *reinterpret_cast<const bf16x8*>(
            &Abuf[cur][(kk * 2 + i) * 512 + l * 8]);
      #pragma unroll
      for (int i = 0; i < 2; ++i)
        #pragma unroll
        for (int j = 0; j < 2; ++j)
          acc[i][j] = __builtin_amdgcn_mfma_f32_16x16x32_bf16(af[i], bfr[j][kk],
                                                              acc[i][j], 0, 0, 0);
    }

    // --- self-exclusion: poison row==col on (rare) diagonal tiles ---
    const int rbase = r0 + tt * RT;
    const int idiff = c0w - rbase;
    if ((unsigned)(idiff + 31) < 63u) {     // wave-uniform branch
      #pragma unroll
      for (int i = 0; i < 2; ++i)
        #pragma unroll
        for (int j = 0; j < 2; ++j) {
          const int dd = idiff + j * 16 + (l & 15) - i * 16 - ((l >> 4) << 2);
          #pragma unroll
          for (int r = 0; r < 4; ++r)
            if (dd == r) acc[i][j][r] = BIGF;   // cndmask after unroll
        }
    }

    // branchless epilogue: 10 VALU ops/key, 2 lists interleaved for ILP
    #pragma unroll
    for (int r = 0; r < 4; ++r)
      #pragma unroll
      for (int i = 0; i < 2; ++i)
        #pragma unroll
        for (int j = 0; j < 2; ++j)
          insM<KNN>(cand[j], acc[i][j][r]);

    asm volatile("" ::: "memory");
    __builtin_amdgcn_s_barrier();    // WAR: all reads of buf done before
    asm volatile("" ::: "memory");   // next iteration overwrites it
  }

  // --- merge the 4 lane-groups holding the same columns (xor 16, then 32) ---
  #pragma unroll
  for (int step = 16; step <= 32; step <<= 1)
    #pragma unroll
    for (int j = 0; j < 2; ++j)
      #pragma unroll
      for (int q = 0; q < KNN; ++q) {
        float o = __shfl_xor(cand[j][q], step, 64);
        insM<KNN>(cand[j], o);
      }

  // --- write slice-partial top-10 ---
  if (l < 16) {
    #pragma unroll
    for (int j = 0; j < 2; ++j) {
      const int c = c0w + j * 16 + l;
      float* dst = partial + ((size_t)(mat * N + c) * NSLICE + slice) * KNN;
      #pragma unroll
      for (int q = 0; q < KNN; ++q) dst[q] = cand[j][q];
    }
  }
}

// ------- Kernel 2: fused slice-merge + sqrt + Sinkhorn (Toeplitz scans) -----
__global__ void sink_kernel(const float* __restrict__ partial,
                            const float* __restrict__ sq,
                            float* __restrict__ ps) {
  int s = blockIdx.x * blockDim.x + threadIdx.x;
  if (s >= N) return;
  constexpr float E1 = 0.36787944117144233f;  // exp(-1)

  float a[KNN], b[KNN];
  #pragma unroll
  for (int m = 0; m < 2; ++m) {
    float best[KNN];
    #pragma unroll
    for (int q = 0; q < KNN; ++q) best[q] = BIGF;
    const float* p = partial + (size_t)(m * N + s) * NSLICE * KNN;
    for (int c = 0; c < NSLICE * KNN; ++c) insP<KNN>(best, p[c]);
    const float sqc = sq[m * N + s];
    float* dst = m ? b : a;
    #pragma unroll
    for (int q = 0; q < KNN; ++q)
      dst[q] = sqrtf(fmaxf(best[q] + sqc, 1e-12f));
  }

  float suma = 0.f, sumb = 0.f;
  #pragma unroll
  for (int q = 0; q < KNN; ++q) { suma += a[q]; sumb += b[q]; }
  float rsa = __builtin_amdgcn_rcpf(suma + EPSF);
  float rsb = __builtin_amdgcn_rcpf(sumb + EPSF);
  #pragma unroll
  for (int q = 0; q < KNN; ++q) { a[q] *= rsa; b[q] *= rsb; }

  float u_[KNN], v_[KNN];
  #pragma unroll
  for (int q = 0; q < KNN; ++q) u_[q] = 1.f;

  #pragma unroll 1
  for (int it = 0; it < 50; ++it) {
    float L[KNN], S[KNN];
    L[0] = u_[0];
    #pragma unroll
    for (int q = 1; q < KNN; ++q) L[q] = fmaf(E1, L[q - 1], u_[q]);
    S[KNN - 1] = u_[KNN - 1];
    #pragma unroll
    for (int q = KNN - 2; q >= 0; --q) S[q] = fmaf(E1, S[q + 1], u_[q]);
    #pragma unroll
    for (int q = 0; q < KNN; ++q) {
      float den = (q < KNN - 1) ? fmaf(E1, S[q + 1], L[q]) : L[KNN - 1];
      v_[q] = b[q] * __builtin_amdgcn_rcpf(den + EPSF);
    }
    L[0] = v_[0];
    #pragma unroll
    for (int q = 1; q < KNN; ++q) L[q] = fmaf(E1, L[q - 1], v_[q]);
    S[KNN - 1] = v_[KNN - 1];
    #pragma unroll
    for (int q = KNN - 2; q >= 0; --q) S[q] = fmaf(E1, S[q + 1], v_[q]);
    #pragma unroll
    for (int q = 0; q < KNN; ++q) {
      float den = (q < KNN - 1) ? fmaf(E1, S[q + 1], L[q]) : L[KNN - 1];
      u_[q] = a[q] * __builtin_amdgcn_rcpf(den + EPSF);
    }
  }
  {
    float L[KNN], S[KNN];
    L[0] = u_[0];
    #pragma unroll
    for (int q = 1; q < KNN; ++q) L[q] = fmaf(E1, L[q - 1], u_[q]);
    S[KNN - 1] = u_[KNN - 1];
    #pragma unroll
    for (int q = KNN - 2; q >= 0; --q) S[q] = fmaf(E1, S[q + 1], u_[q]);
    #pragma unroll
    for (int q = 0; q < KNN; ++q) {
      float den = (q < KNN - 1) ? fmaf(E1, S[q + 1], L[q]) : L[KNN - 1];
      v_[q] = b[q] * __builtin_amdgcn_rcpf(den + EPSF);
    }
  }
  float cost = 0.f;
  #pragma unroll
  for (int i = 0; i < KNN; ++i) {
    float accr = 0.f;
    #pragma unroll
    for (int j = 0; j < KNN; ++j) {
      const int dd = i > j ? i - j : j - i;
      const float wgt = 0.1f * (float)dd * __builtin_expf(-(float)dd); // folds
      accr = fmaf(wgt, v_[j], accr);
    }
    cost = fmaf(u_[i], accr, cost);
  }
  ps[s] = cost;
}

// ---------------- Kernel 3: mean reduce ----------------
__global__ void reduce_kernel(const float* __restrict__ ps, float* __restrict__ out) {
  __shared__ float red[256];
  int tid = threadIdx.x;
  float s = 0.f;
  for (int i = tid; i < N; i += 256) s += ps[i];
  red[tid] = s;
  __syncthreads();
  #pragma unroll
  for (int off = 128; off > 0; off >>= 1) {
    if (tid < off) red[tid] += red[tid + off];
    __syncthreads();
  }
  if (tid == 0) out[0] = red[0] * (1.0f / N);
}

extern "C" void kernel_launch(void* const* d_in, const int* in_sizes, int n_in,
                              void* d_out, int out_size, void* d_ws, size_t ws_size,
                              hipStream_t stream) {
  const float* xc = (const float*)d_in[0];
  const float* xr = (const float*)d_in[1];
  float* out = (float*)d_out;
  char* wsb = (char*)d_ws;

  float* sq       = (float*)wsb;                                // 2N f32 (64KB)
  ushort_t* xb    = (ushort_t*)(wsb + (1u << 16));              // 4MB
  ushort_t* xa    = (ushort_t*)(wsb + (1u << 16) + (4u << 20)); // 4MB
  float* partial  = (float*)(wsb + (1u << 16) + (8u << 20));    // 2N*80 f32
  float* ps       = partial + (size_t)2 * N * NSLICE * KNN;     // N f32

  prep_kernel<<<dim3(2 * N / 4), dim3(256), 0, stream>>>(xc, xr, xb, xa, sq);
  knn_mfma<<<dim3(1024), dim3(256), 0, stream>>>(xb, xa, sq, partial);
  sink_kernel<<<dim3(N / 64), dim3(64), 0, stream>>>(partial, sq, ps);
  reduce_kernel<<<dim3(1), dim3(256), 0, stream>>>(ps, out);
}